// Round 1
// baseline (141.396 us; speedup 1.0000x reference)
//
#include <hip/hip_runtime.h>

#define NN 256
#define NITER 20

static constexpr float K2 = 14.426950408889634f; // (1/tau) * log2(e), tau = 0.1

struct Smem {
  float ref[NN];
  float xs[NN];
  float P[NN];
  float Q[NN];
  float red[16];
  int   orig[NN];
};

__global__ __launch_bounds__(NN, 4)
void sinkhorn_sort_kernel(const float* __restrict__ x,
                          const float* __restrict__ xn,
                          const float* __restrict__ refv,
                          float* __restrict__ out)
{
  __shared__ Smem sm;
  const int tid  = threadIdx.x;
  const int lane = tid & 63;
  const int wid  = tid >> 6;
  const long long b = blockIdx.x;

  const float xT   = x[b * NN + tid];
  const float xnT  = xn[b * NN + tid];
  const float refT = refv[tid];
  sm.ref[tid] = refT;
  sm.P[tid]   = xnT;   // temp: xn values for ranking
  __syncthreads();

  // stable rank sort of xn (O(N) per thread, once per batch)
  int rank = 0;
  #pragma unroll 8
  for (int l = 0; l < NN; ++l) {
    float v = sm.P[l];
    rank += (int)((v < xnT) || (v == xnT && l < tid));
  }
  sm.xs[rank]   = xnT;
  sm.orig[rank] = tid;
  __syncthreads();

  const float xsT  = sm.xs[tid];   // sorted row value owned by this thread
  const int  origT = sm.orig[tid];

  // split indices (iteration-invariant):
  // j0 = last j with ref[j] <= xs[tid]
  int lo = 0, hi = NN;
  while (lo < hi) { int mid = (lo + hi) >> 1; if (sm.ref[mid] <= xsT) lo = mid + 1; else hi = mid; }
  const int j0 = lo - 1;
  // m0 = last m with xs[m] <= ref[tid]
  lo = 0; hi = NN;
  while (lo < hi) { int mid = (lo + hi) >> 1; if (sm.xs[mid] <= refT) lo = mid + 1; else hi = mid; }
  const int m0 = lo - 1;

  float R2 = 0.0f;  // base-2 row potential for sorted row m = tid
  float C2 = 0.0f;  // base-2 col potential for col j = tid

  // One Sinkhorn half-pass in O(N): terms indexed by tid (ascending position),
  // prefix/suffix scans, then evaluate LSE (or weighted sum) at `split`.
  auto pass = [&](float termPos, float termPot, float w, float evalPos, int split, bool lse) -> float {
    const float a  = fmaf( K2, termPos, -termPot);  //  k*pos - pot
    const float bb = fmaf(-K2, termPos, -termPot);  // -k*pos - pot
    // block-wide max of both (stabilization shifts)
    float ma = a, mb = bb;
    #pragma unroll
    for (int d = 1; d < 64; d <<= 1) {
      ma = fmaxf(ma, __shfl_xor(ma, d, 64));
      mb = fmaxf(mb, __shfl_xor(mb, d, 64));
    }
    if (lane == 0) { sm.red[wid] = ma; sm.red[4 + wid] = mb; }
    __syncthreads();
    const float SP = fmaxf(fmaxf(sm.red[0], sm.red[1]), fmaxf(sm.red[2], sm.red[3]));
    const float SQ = fmaxf(fmaxf(sm.red[4], sm.red[5]), fmaxf(sm.red[6], sm.red[7]));
    float pa = exp2f(a  - SP) * w;
    float qb = exp2f(bb - SQ) * w;
    // wave-level inclusive prefix (pa) and suffix (qb) scans
    #pragma unroll
    for (int d = 1; d < 64; d <<= 1) {
      float tP = __shfl_up(pa, (unsigned)d, 64);
      float tQ = __shfl_down(qb, (unsigned)d, 64);
      if (lane >= d)     pa += tP;
      if (lane + d < 64) qb += tQ;
    }
    if (lane == 63) sm.red[8 + wid]  = pa;  // wave totals (prefix)
    if (lane == 0)  sm.red[12 + wid] = qb;  // wave totals (suffix)
    __syncthreads();
    float offP = 0.0f, offQ = 0.0f;
    #pragma unroll
    for (int wv = 0; wv < 4; ++wv) {
      if (wv < wid) offP += sm.red[8 + wv];
      if (wv > wid) offQ += sm.red[12 + wv];
    }
    sm.P[tid] = pa + offP;
    sm.Q[tid] = qb + offQ;
    __syncthreads();
    float r;
    if (lse) {
      float e1 = -1e38f, e2 = -1e38f;
      if (split >= 0)     e1 = fmaf(-K2, evalPos, SP) + log2f(sm.P[split]);
      if (split < NN - 1) e2 = fmaf( K2, evalPos, SQ) + log2f(sm.Q[split + 1]);
      const float mx = fmaxf(e1, e2);
      const float mn = fminf(e1, e2);
      r = mx + log2f(1.0f + exp2f(mn - mx));
    } else {
      float v1 = 0.0f, v2 = 0.0f;
      if (split >= 0)     v1 = exp2f(fmaf(-K2, evalPos, SP) - R2) * sm.P[split];
      if (split < NN - 1) v2 = exp2f(fmaf( K2, evalPos, SQ) - R2) * sm.Q[split + 1];
      r = v1 + v2;
    }
    __syncthreads();
    return r;
  };

  for (int it = 0; it < NITER; ++it) {
    // row pass: R[m] = LSE_j(A0[m,j] - C[j]) ; terms over j (= tid, ref ascending)
    R2 = pass(refT, C2, 1.0f, xsT, j0, true);
    // col pass: C[j] = LSE_m(A0[m,j] - R[m]) ; terms over sorted m (= tid, xs ascending)
    C2 = pass(xsT, R2, 1.0f, refT, m0, true);
  }
  // final: out[orig(m)] = sum_j 2^(A0[m,j] - R[m] - C[j]) * x[j]
  const float o = pass(refT, C2, xT, xsT, j0, false);
  out[b * NN + origT] = o;
}

extern "C" void kernel_launch(void* const* d_in, const int* in_sizes, int n_in,
                              void* d_out, int out_size, void* d_ws, size_t ws_size,
                              hipStream_t stream) {
  const float* x    = (const float*)d_in[0];
  const float* xnrm = (const float*)d_in[1];
  const float* refv = (const float*)d_in[2];
  float* out = (float*)d_out;
  const int B = in_sizes[0] / NN;  // 2048
  sinkhorn_sort_kernel<<<dim3(B), dim3(NN), 0, stream>>>(x, xnrm, refv, out);
}

// Round 2
// 31.337 us; speedup vs baseline: 4.5121x; 4.5121x over previous
//
#include <hip/hip_runtime.h>

#define NN 256
#define NITER 20
static constexpr float KK = 14.426950408889634f; // (1/tau)*log2(e), tau=0.1

template<int CTRL>
__device__ __forceinline__ float dppadd(float x) {
  int v = __builtin_amdgcn_update_dpp(0, __float_as_int(x), CTRL, 0xF, 0xF, true);
  return x + __int_as_float(v);
}
__device__ __forceinline__ float rlane(float v, int l) {
  return __int_as_float(__builtin_amdgcn_readlane(__float_as_int(v), l));
}
__device__ __forceinline__ float rcpf(float x) {
  float r; asm("v_rcp_f32 %0, %1" : "=v"(r) : "v"(x)); return r;
}

__global__ __launch_bounds__(64)
void sinkhorn_wave(const float* __restrict__ x,
                   const float* __restrict__ xn,
                   const float* __restrict__ refv,
                   float* __restrict__ out)
{
  // per-block (= per-wave, = per-batch) LDS
  __shared__ float Parr[260];                 // prefix sums, [0..3] = 0-pad, P_incl[j] at [4+j]
  __shared__ float Qarr[260];                 // suffix sums, Q_incl[j] at [j], [256..259] = 0-pad
  __shared__ float aux[NN];                   // sorted (clamped) xn
  __shared__ unsigned long long keys[NN];     // sortable keys
  __shared__ int origArr[NN];                 // original index per sorted slot

  const int lane = threadIdx.x;               // 0..63
  const long long b = blockIdx.x;
  const int j4 = lane * 4;

  float xnv[4], xv[4], rv[4];
  { float4 t = *(const float4*)(xn + b * NN + j4); xnv[0]=t.x; xnv[1]=t.y; xnv[2]=t.z; xnv[3]=t.w; }
  { float4 t = *(const float4*)(x  + b * NN + j4); xv[0]=t.x;  xv[1]=t.y;  xv[2]=t.z;  xv[3]=t.w; }
  { float4 t = *(const float4*)(refv + j4);        rv[0]=t.x;  rv[1]=t.y;  rv[2]=t.z;  rv[3]=t.w; }

  // ---- rank sort of xn via sortable u64 keys (value<<32 | idx; tie-safe) ----
  unsigned long long mykey[4];
  #pragma unroll
  for (int t = 0; t < 4; ++t) {
    unsigned u = __float_as_uint(xnv[t]);
    unsigned m = (u & 0x80000000u) ? ~u : (u | 0x80000000u);
    mykey[t] = ((unsigned long long)m << 32) | (unsigned)(j4 + t);
    keys[j4 + t] = mykey[t];
  }
  __syncthreads();
  int rank[4] = {0,0,0,0};
  for (int l = 0; l < NN; l += 4) {
    unsigned long long k0 = keys[l], k1 = keys[l+1], k2 = keys[l+2], k3 = keys[l+3];
    #pragma unroll
    for (int t = 0; t < 4; ++t)
      rank[t] += (int)(k0 < mykey[t]) + (int)(k1 < mykey[t]) +
                 (int)(k2 < mykey[t]) + (int)(k3 < mykey[t]);
  }
  __syncthreads();  // all key reads done before reusing LDS
  // scatter: sorted clamped values + original indices; stage ref into Parr for search
  #pragma unroll
  for (int t = 0; t < 4; ++t) {
    float vc = fminf(fmaxf(xnv[t], -1.0f), 1.0f);  // clamp: exact row-shift invariance
    aux[rank[t]] = vc;
    origArr[rank[t]] = j4 + t;
    Parr[j4 + t] = rv[t];                           // ref array (temp) for j0 search
  }
  __syncthreads();
  float xs[4]; int orig[4];
  #pragma unroll
  for (int t = 0; t < 4; ++t) { xs[t] = aux[j4 + t]; orig[t] = origArr[j4 + t]; }

  // split indices (iteration-invariant)
  int j0[4], m0[4];
  #pragma unroll
  for (int t = 0; t < 4; ++t) {
    int lo = 0, hi = NN;
    #pragma unroll
    for (int s = 0; s < 8; ++s) { int mid = (lo + hi) >> 1; bool c = (Parr[mid] <= xs[t]); lo = c ? (mid + 1) : lo; hi = c ? hi : mid; }
    j0[t] = lo - 1;                                 // last j: ref[j] <= xs[t]
    lo = 0; hi = NN;
    #pragma unroll
    for (int s = 0; s < 8; ++s) { int mid = (lo + hi) >> 1; bool c = (aux[mid] <= rv[t]); lo = c ? (mid + 1) : lo; hi = c ? hi : mid; }
    m0[t] = lo - 1;                                 // last m: xs[m] <= ref[t]
  }
  __syncthreads();
  if (lane == 0) {
    Parr[0] = Parr[1] = Parr[2] = Parr[3] = 0.f;
    Qarr[256] = Qarr[257] = Qarr[258] = Qarr[259] = 0.f;
  }
  // precomputed exponential factors (setup-only transcendentals)
  float Ep[4], Em[4], Epx[4], Emx[4];
  #pragma unroll
  for (int t = 0; t < 4; ++t) {
    Ep[t]  = exp2f( KK * rv[t]);  Em[t]  = exp2f(-KK * rv[t]);
    Epx[t] = exp2f( KK * xs[t]);  Emx[t] = exp2f(-KK * xs[t]);
  }
  __syncthreads();

  // scan + store: Parr gets inclusive prefix of pa, Qarr inclusive suffix of qb
  auto scan_store = [&](const float (&pa)[4], const float (&qb)[4]) {
    float ip0 = pa[0], ip1 = ip0 + pa[1], ip2 = ip1 + pa[2], ip3 = ip2 + pa[3];
    float sq3 = qb[3], sq2 = sq3 + qb[2], sq1 = sq2 + qb[1], sq0 = sq1 + qb[0];
    float offP, offQ;
    { float s = ip3;                                 // wave prefix over lane totals (DPP)
      s = dppadd<0x111>(s); s = dppadd<0x112>(s); s = dppadd<0x114>(s); s = dppadd<0x118>(s);
      float r0 = rlane(s, 15), r1 = rlane(s, 31), r2 = rlane(s, 47);
      int row = lane >> 4;
      offP = (s - ip3) + ((row >= 1) ? r0 : 0.f) + ((row >= 2) ? r1 : 0.f) + ((row >= 3) ? r2 : 0.f);
    }
    { float s = sq0;                                 // wave suffix over lane totals (DPP)
      s = dppadd<0x101>(s); s = dppadd<0x102>(s); s = dppadd<0x104>(s); s = dppadd<0x108>(s);
      float q1 = rlane(s, 16), q2 = rlane(s, 32), q3 = rlane(s, 48);
      int row = lane >> 4;
      offQ = (s - sq0) + ((row <= 0) ? q1 : 0.f) + ((row <= 1) ? q2 : 0.f) + ((row <= 2) ? q3 : 0.f);
    }
    float4 pw = make_float4(offP + ip0, offP + ip1, offP + ip2, offP + ip3);
    float4 qw = make_float4(offQ + sq0, offQ + sq1, offQ + sq2, offQ + sq3);
    *(float4*)&Parr[4 + j4] = pw;   // ds_write_b128, aligned
    *(float4*)&Qarr[j4]     = qw;
  };

  float vC[4] = {1.f, 1.f, 1.f, 1.f}, vR[4];
  for (int it = 0; it < NITER; ++it) {
    { // row pass: vR[m] = 1 / sum_j 2^{-k|xs_m - ref_j|} vC_j
      float pa[4], qb[4];
      #pragma unroll
      for (int t = 0; t < 4; ++t) { pa[t] = Ep[t] * vC[t]; qb[t] = Em[t] * vC[t]; }
      scan_store(pa, qb);
      __syncthreads();
      #pragma unroll
      for (int t = 0; t < 4; ++t) {
        float S = Emx[t] * Parr[4 + j0[t]] + Epx[t] * Qarr[j0[t] + 1];
        vR[t] = rcpf(S);
      }
      __syncthreads();
    }
    { // col pass: vC[j] = 1 / sum_m 2^{-k|xs_m - ref_j|} vR_m
      float pa[4], qb[4];
      #pragma unroll
      for (int t = 0; t < 4; ++t) { pa[t] = Epx[t] * vR[t]; qb[t] = Emx[t] * vR[t]; }
      scan_store(pa, qb);
      __syncthreads();
      #pragma unroll
      for (int t = 0; t < 4; ++t) {
        float S = Em[t] * Parr[4 + m0[t]] + Ep[t] * Qarr[m0[t] + 1];
        vC[t] = rcpf(S);
      }
      __syncthreads();
    }
  }
  { // final weighted row pass: out[orig_m] = vR_m * sum_j 2^{-k|xs_m - ref_j|} vC_j x_j
    float pa[4], qb[4];
    #pragma unroll
    for (int t = 0; t < 4; ++t) { float w = Em[t] * vC[t] * xv[t]; pa[t] = Ep[t] * vC[t] * xv[t]; qb[t] = w; }
    scan_store(pa, qb);
    __syncthreads();
    #pragma unroll
    for (int t = 0; t < 4; ++t) {
      float S = Emx[t] * Parr[4 + j0[t]] + Epx[t] * Qarr[j0[t] + 1];
      out[b * NN + orig[t]] = vR[t] * S;
    }
  }
}

extern "C" void kernel_launch(void* const* d_in, const int* in_sizes, int n_in,
                              void* d_out, int out_size, void* d_ws, size_t ws_size,
                              hipStream_t stream) {
  const float* x    = (const float*)d_in[0];
  const float* xnrm = (const float*)d_in[1];
  const float* refv = (const float*)d_in[2];
  float* out = (float*)d_out;
  const int B = in_sizes[0] / NN;  // 2048
  sinkhorn_wave<<<dim3(B), dim3(64), 0, stream>>>(x, xnrm, refv, out);
}

// Round 3
// 30.715 us; speedup vs baseline: 4.6034x; 1.0202x over previous
//
#include <hip/hip_runtime.h>

#define NN 256
#define NITER 20
static constexpr float KK = 14.426950408889634f; // (1/tau)*log2(e), tau=0.1

template<int CTRL, int RM>
__device__ __forceinline__ float dppadd(float x) {
  int v = __builtin_amdgcn_update_dpp(0, __float_as_int(x), CTRL, RM, 0xF, true);
  return x + __int_as_float(v);
}
__device__ __forceinline__ float rlane(float v, int l) {
  return __int_as_float(__builtin_amdgcn_readlane(__float_as_int(v), l));
}
__device__ __forceinline__ float rcpf(float x) {
  float r; asm("v_rcp_f32 %0, %1" : "=v"(r) : "v"(x)); return r;
}

__global__ __launch_bounds__(64)
void sinkhorn_wave(const float* __restrict__ x,
                   const float* __restrict__ xn,
                   const float* __restrict__ refv,
                   float* __restrict__ out)
{
  // Single-wave workgroup: NO __syncthreads anywhere. Correctness relies on
  // (a) wave64 lockstep execution, (b) per-wave in-order LDS processing,
  // (c) compiler preserving order of may-alias LDS ops (dynamic indices).
  __shared__ __align__(16) float2 W[258];              // slot i in [0,256]: (P_excl[i], Q_incl[i])
  __shared__ __align__(16) unsigned long long keys[NN];
  __shared__ float refArr[NN];
  __shared__ float xsArr[NN];
  __shared__ int   origArr[NN];

  const int lane = threadIdx.x;   // 0..63
  const long long b = blockIdx.x;
  const int j4 = lane * 4;

  float xnv[4], xv[4], rv[4];
  { float4 t = *(const float4*)(xn + b * NN + j4); xnv[0]=t.x; xnv[1]=t.y; xnv[2]=t.z; xnv[3]=t.w; }
  { float4 t = *(const float4*)(x  + b * NN + j4); xv[0]=t.x;  xv[1]=t.y;  xv[2]=t.z;  xv[3]=t.w; }
  { float4 t = *(const float4*)(refv + j4);        rv[0]=t.x;  rv[1]=t.y;  rv[2]=t.z;  rv[3]=t.w; }

  // ---- rank sort of xn via sortable u64 keys (monotone-float<<32 | idx) ----
  unsigned long long mykey[4];
  #pragma unroll
  for (int t = 0; t < 4; ++t) {
    unsigned u = __float_as_uint(xnv[t]);
    unsigned m = (u & 0x80000000u) ? ~u : (u | 0x80000000u);
    mykey[t] = ((unsigned long long)m << 32) | (unsigned)(j4 + t);
    keys[j4 + t] = mykey[t];
    refArr[j4 + t] = rv[t];
  }
  int rank[4] = {0, 0, 0, 0};
  #pragma unroll 2
  for (int l = 0; l < NN; l += 4) {
    unsigned long long k0 = keys[l], k1 = keys[l+1], k2 = keys[l+2], k3 = keys[l+3];
    #pragma unroll
    for (int t = 0; t < 4; ++t)
      rank[t] += (int)(k0 < mykey[t]) + (int)(k1 < mykey[t]) +
                 (int)(k2 < mykey[t]) + (int)(k3 < mykey[t]);
  }
  #pragma unroll
  for (int t = 0; t < 4; ++t) {
    float vc = fminf(fmaxf(xnv[t], -1.0f), 1.0f);   // clamp = exact row-shift invariance
    xsArr[rank[t]]   = vc;
    origArr[rank[t]] = j4 + t;
  }
  float xs[4]; int orig[4];
  #pragma unroll
  for (int t = 0; t < 4; ++t) { xs[t] = xsArr[j4 + t]; orig[t] = origArr[j4 + t]; }

  // split slots (iteration-invariant): slotJ = j0+1, slotM = m0+1
  int slotJ[4], slotM[4];
  #pragma unroll
  for (int t = 0; t < 4; ++t) {
    int lo = 0, hi = NN;
    #pragma unroll
    for (int s = 0; s < 8; ++s) { int mid = (lo + hi) >> 1; bool c = (refArr[mid] <= xs[t]); lo = c ? (mid + 1) : lo; hi = c ? hi : mid; }
    slotJ[t] = lo;                                  // = j0+1, j0 = last j: ref[j] <= xs[t]
    lo = 0; hi = NN;
    #pragma unroll
    for (int s = 0; s < 8; ++s) { int mid = (lo + hi) >> 1; bool c = (xsArr[mid] <= rv[t]); lo = c ? (mid + 1) : lo; hi = c ? hi : mid; }
    slotM[t] = lo;                                  // = m0+1, m0 = last m: xs[m] <= ref[t]
  }

  // precomputed exponential factors (setup-only transcendentals)
  float Ep[4], Em[4], Epx[4], Emx[4];
  #pragma unroll
  for (int t = 0; t < 4; ++t) {
    Ep[t]  = exp2f( KK * rv[t]);  Em[t]  = exp2f(-KK * rv[t]);
    Epx[t] = exp2f( KK * xs[t]);  Emx[t] = exp2f(-KK * xs[t]);
  }

  // scan + store: W[i] = (P_excl[i], Q_incl[i]) for i in [0,256].
  // P_excl[j4..j4+3] are lane-local: offP, offP+ip0, offP+ip1, offP+ip2.
  // Slot 256 written by lane 63 only (P_excl[256]=total, Q_incl[256]=0).
  auto scan_store = [&](float pa0, float pa1, float pa2, float pa3,
                        float qb0, float qb1, float qb2, float qb3) {
    float ip0 = pa0, ip1 = ip0 + pa1, ip2 = ip1 + pa2, ip3 = ip2 + pa3;
    float sq3 = qb3, sq2 = sq3 + qb2, sq1 = sq2 + qb1, sq0 = sq1 + qb0;
    // inclusive prefix over lane totals: 4 row_shr + bcast15 + bcast31
    float sP = ip3;
    sP = dppadd<0x111, 0xF>(sP);
    sP = dppadd<0x112, 0xF>(sP);
    sP = dppadd<0x114, 0xF>(sP);
    sP = dppadd<0x118, 0xF>(sP);
    sP = dppadd<0x142, 0xA>(sP);   // ROW_BCAST15 -> rows 1,3
    sP = dppadd<0x143, 0xC>(sP);   // ROW_BCAST31 -> rows 2,3
    float offP = sP - ip3;
    // inclusive suffix: 4 row_shl (within-row) + 3 readlane row totals
    float sQ = sq0;
    sQ = dppadd<0x101, 0xF>(sQ);
    sQ = dppadd<0x102, 0xF>(sQ);
    sQ = dppadd<0x104, 0xF>(sQ);
    sQ = dppadd<0x108, 0xF>(sQ);
    float q1 = rlane(sQ, 16), q2 = rlane(sQ, 32), q3 = rlane(sQ, 48);
    int row = lane >> 4;
    float offQ = sQ - sq0;
    offQ += (row < 1) ? q1 : 0.f;
    offQ += (row < 2) ? q2 : 0.f;
    offQ += (row < 3) ? q3 : 0.f;
    float4 w0 = make_float4(offP,       offQ + sq0, offP + ip0, offQ + sq1);
    float4 w1 = make_float4(offP + ip1, offQ + sq2, offP + ip2, offQ + sq3);
    *(float4*)&W[j4]     = w0;
    *(float4*)&W[j4 + 2] = w1;
    if (lane == 63) W[256] = make_float2(sP, 0.f);
  };

  float vC[4] = {1.f, 1.f, 1.f, 1.f}, vR[4];
  #pragma unroll 1
  for (int it = 0; it < NITER; ++it) {
    // row pass: vR[m] = 1 / (Emx*P_excl[slotJ] + Epx*Q_incl[slotJ])
    scan_store(Ep[0]*vC[0], Ep[1]*vC[1], Ep[2]*vC[2], Ep[3]*vC[3],
               Em[0]*vC[0], Em[1]*vC[1], Em[2]*vC[2], Em[3]*vC[3]);
    #pragma unroll
    for (int t = 0; t < 4; ++t) {
      float2 w = W[slotJ[t]];
      vR[t] = rcpf(fmaf(Emx[t], w.x, Epx[t] * w.y));
    }
    // col pass: vC[j] = 1 / (Em*P_excl[slotM] + Ep*Q_incl[slotM])
    scan_store(Epx[0]*vR[0], Epx[1]*vR[1], Epx[2]*vR[2], Epx[3]*vR[3],
               Emx[0]*vR[0], Emx[1]*vR[1], Emx[2]*vR[2], Emx[3]*vR[3]);
    #pragma unroll
    for (int t = 0; t < 4; ++t) {
      float2 w = W[slotM[t]];
      vC[t] = rcpf(fmaf(Em[t], w.x, Ep[t] * w.y));
    }
  }
  // final weighted row pass: out[orig_m] = vR_m * sum_j 2^{-k|xs_m-ref_j|} vC_j x_j
  {
    float g0 = vC[0]*xv[0], g1 = vC[1]*xv[1], g2 = vC[2]*xv[2], g3 = vC[3]*xv[3];
    scan_store(Ep[0]*g0, Ep[1]*g1, Ep[2]*g2, Ep[3]*g3,
               Em[0]*g0, Em[1]*g1, Em[2]*g2, Em[3]*g3);
    #pragma unroll
    for (int t = 0; t < 4; ++t) {
      float2 w = W[slotJ[t]];
      float S = fmaf(Emx[t], w.x, Epx[t] * w.y);
      out[b * NN + orig[t]] = vR[t] * S;
    }
  }
}

extern "C" void kernel_launch(void* const* d_in, const int* in_sizes, int n_in,
                              void* d_out, int out_size, void* d_ws, size_t ws_size,
                              hipStream_t stream) {
  const float* x    = (const float*)d_in[0];
  const float* xnrm = (const float*)d_in[1];
  const float* refv = (const float*)d_in[2];
  float* out = (float*)d_out;
  const int B = in_sizes[0] / NN;  // 2048
  sinkhorn_wave<<<dim3(B), dim3(64), 0, stream>>>(x, xnrm, refv, out);
}

// Round 4
// 21.140 us; speedup vs baseline: 6.6885x; 1.4529x over previous
//
#include <hip/hip_runtime.h>

#define NN 256
#define NITER 20
static constexpr float KK = 14.426950408889634f; // (1/tau)*log2(e), tau=0.1

template<int CTRL, int RM>
__device__ __forceinline__ float dppadd(float x) {
  int v = __builtin_amdgcn_update_dpp(0, __float_as_int(x), CTRL, RM, 0xF, true);
  return x + __int_as_float(v);
}
template<int CTRL, int RM>
__device__ __forceinline__ int dppaddi(int x) {
  int v = __builtin_amdgcn_update_dpp(0, x, CTRL, RM, 0xF, true);
  return x + v;
}
__device__ __forceinline__ float rlane(float v, int l) {
  return __int_as_float(__builtin_amdgcn_readlane(__float_as_int(v), l));
}
__device__ __forceinline__ float rcpf(float x) {
  float r; asm("v_rcp_f32 %0, %1" : "=v"(r) : "v"(x)); return r;
}

__global__ __launch_bounds__(64)
void sinkhorn_wave(const float* __restrict__ x,
                   const float* __restrict__ xn,
                   const float* __restrict__ refv,
                   float* __restrict__ out)
{
  // Single-wave workgroup: no __syncthreads. Per-wave in-order DS processing
  // guarantees LDS RAW ordering; compiler preserves program order on
  // may-aliasing LDS ops.
  __shared__ __align__(16) float2   W[258];     // slot i in [0,256]: (P_excl[i], Q_incl[i])
  __shared__ __align__(16) unsigned hist[NN];   // bucket counts
  __shared__ __align__(16) int      exclArr[NN];// exclusive bucket prefix
  __shared__ __align__(16) float    xsArr[NN];  // bucket-grouped clamped xn
  __shared__ __align__(16) int      origArr[NN];// original row index per slot

  const int lane = threadIdx.x;   // 0..63
  const int b = blockIdx.x;
  const int j4 = lane * 4;
  const size_t base = (size_t)b * NN;

  float xnv[4], xv[4], rv[4];
  { float4 t = *(const float4*)(xn + base + j4); xnv[0]=t.x; xnv[1]=t.y; xnv[2]=t.z; xnv[3]=t.w; }
  { float4 t = *(const float4*)(x  + base + j4); xv[0]=t.x;  xv[1]=t.y;  xv[2]=t.z;  xv[3]=t.w; }
  { float4 t = *(const float4*)(refv + j4);      rv[0]=t.x;  rv[1]=t.y;  rv[2]=t.z;  rv[3]=t.w; }

  // ---- bucket-group rows by grid cell (replaces sort; intra-bucket order is free) ----
  *(uint4*)&hist[j4] = make_uint4(0u, 0u, 0u, 0u);          // zero hist (in-order DS)
  float vc[4]; int cb[4]; unsigned rtn[4];
  #pragma unroll
  for (int t = 0; t < 4; ++t) {
    vc[t] = fminf(fmaxf(xnv[t], -1.0f), 1.0f);              // clamp = exact row-shift invariance
    cb[t] = (int)fmaf(vc[t], 127.5f, 127.5f);               // bucket in [0,255]
    rtn[t] = atomicAdd(&hist[cb[t]], 1u);                   // intra-bucket position
  }
  // exclusive prefix of hist (int DPP scan); lane owns buckets j4..j4+3
  uint4 hv = *(uint4*)&hist[j4];                             // after all atomics (in-order)
  int ih0 = (int)hv.x, ih1 = ih0 + (int)hv.y, ih2 = ih1 + (int)hv.z, ih3 = ih2 + (int)hv.w;
  int sH = ih3;
  sH = dppaddi<0x111, 0xF>(sH);
  sH = dppaddi<0x112, 0xF>(sH);
  sH = dppaddi<0x114, 0xF>(sH);
  sH = dppaddi<0x118, 0xF>(sH);
  sH = dppaddi<0x142, 0xA>(sH);   // ROW_BCAST15 -> rows 1,3
  sH = dppaddi<0x143, 0xC>(sH);   // ROW_BCAST31 -> rows 2,3
  const int offH = sH - ih3;
  // col-pass split slots are the lane's OWN exclusive values (no LDS gather)
  int slotM[4] = { offH, offH + ih0, offH + ih1, offH + ih2 };
  *(int4*)&exclArr[j4] = make_int4(slotM[0], slotM[1], slotM[2], slotM[3]);
  // scatter rows to bucket-grouped slots
  #pragma unroll
  for (int t = 0; t < 4; ++t) {
    int slot = exclArr[cb[t]] + (int)rtn[t];
    xsArr[slot]   = vc[t];
    origArr[slot] = j4 + t;
  }
  // readback owned slots
  float xs[4]; int orig[4];
  { float4 t = *(float4*)&xsArr[j4]; xs[0]=t.x; xs[1]=t.y; xs[2]=t.z; xs[3]=t.w; }
  { int4  t = *(int4*)&origArr[j4]; orig[0]=t.x; orig[1]=t.y; orig[2]=t.z; orig[3]=t.w; }

  // row-pass split slots: closed form (ties harmless — both sides give 2^0)
  int slotJ[4];
  #pragma unroll
  for (int t = 0; t < 4; ++t) slotJ[t] = (int)fmaf(xs[t], 127.5f, 127.5f) + 1;  // in [1,256]

  // precomputed exponential factors (setup-only transcendentals)
  float Ep[4], Em[4], Epx[4], Emx[4];
  #pragma unroll
  for (int t = 0; t < 4; ++t) {
    Ep[t]  = exp2f( KK * rv[t]);  Em[t]  = exp2f(-KK * rv[t]);
    Epx[t] = exp2f( KK * xs[t]);  Emx[t] = exp2f(-KK * xs[t]);
  }

  // scan + store: W[i] = (P_excl[i], Q_incl[i]) for i in [0,256]
  auto scan_store = [&](float pa0, float pa1, float pa2, float pa3,
                        float qb0, float qb1, float qb2, float qb3) {
    float ip0 = pa0, ip1 = ip0 + pa1, ip2 = ip1 + pa2, ip3 = ip2 + pa3;
    float sq3 = qb3, sq2 = sq3 + qb2, sq1 = sq2 + qb1, sq0 = sq1 + qb0;
    float sP = ip3;                     // inclusive prefix over lane totals
    sP = dppadd<0x111, 0xF>(sP);
    sP = dppadd<0x112, 0xF>(sP);
    sP = dppadd<0x114, 0xF>(sP);
    sP = dppadd<0x118, 0xF>(sP);
    sP = dppadd<0x142, 0xA>(sP);
    sP = dppadd<0x143, 0xC>(sP);
    float offP = sP - ip3;
    float sQ = sq0;                     // inclusive suffix within rows
    sQ = dppadd<0x101, 0xF>(sQ);
    sQ = dppadd<0x102, 0xF>(sQ);
    sQ = dppadd<0x104, 0xF>(sQ);
    sQ = dppadd<0x108, 0xF>(sQ);
    float q1 = rlane(sQ, 16), q2 = rlane(sQ, 32), q3 = rlane(sQ, 48);
    int row = lane >> 4;
    float offQ = sQ - sq0;
    offQ += (row < 1) ? q1 : 0.f;
    offQ += (row < 2) ? q2 : 0.f;
    offQ += (row < 3) ? q3 : 0.f;
    float4 w0 = make_float4(offP,       offQ + sq0, offP + ip0, offQ + sq1);
    float4 w1 = make_float4(offP + ip1, offQ + sq2, offP + ip2, offQ + sq3);
    *(float4*)&W[j4]     = w0;
    *(float4*)&W[j4 + 2] = w1;
    if (lane == 63) W[256] = make_float2(sP, 0.f);
  };

  float vC[4] = {1.f, 1.f, 1.f, 1.f}, vR[4];
  #pragma unroll 1
  for (int it = 0; it < NITER; ++it) {
    // row pass: vR[m] = 1 / (Emx*P_excl[slotJ] + Epx*Q_incl[slotJ])
    scan_store(Ep[0]*vC[0], Ep[1]*vC[1], Ep[2]*vC[2], Ep[3]*vC[3],
               Em[0]*vC[0], Em[1]*vC[1], Em[2]*vC[2], Em[3]*vC[3]);
    #pragma unroll
    for (int t = 0; t < 4; ++t) {
      float2 w = W[slotJ[t]];
      vR[t] = rcpf(fmaf(Emx[t], w.x, Epx[t] * w.y));
    }
    // col pass: vC[j] = 1 / (Em*P_excl[slotM] + Ep*Q_incl[slotM])
    scan_store(Epx[0]*vR[0], Epx[1]*vR[1], Epx[2]*vR[2], Epx[3]*vR[3],
               Emx[0]*vR[0], Emx[1]*vR[1], Emx[2]*vR[2], Emx[3]*vR[3]);
    #pragma unroll
    for (int t = 0; t < 4; ++t) {
      float2 w = W[slotM[t]];
      vC[t] = rcpf(fmaf(Em[t], w.x, Ep[t] * w.y));
    }
  }
  // final weighted row pass: out[orig_m] = vR_m * sum_j 2^{-k|xs_m-ref_j|} vC_j x_j
  {
    float g0 = vC[0]*xv[0], g1 = vC[1]*xv[1], g2 = vC[2]*xv[2], g3 = vC[3]*xv[3];
    scan_store(Ep[0]*g0, Ep[1]*g1, Ep[2]*g2, Ep[3]*g3,
               Em[0]*g0, Em[1]*g1, Em[2]*g2, Em[3]*g3);
    #pragma unroll
    for (int t = 0; t < 4; ++t) {
      float2 w = W[slotJ[t]];
      float S = fmaf(Emx[t], w.x, Epx[t] * w.y);
      out[base + orig[t]] = vR[t] * S;
    }
  }
}

extern "C" void kernel_launch(void* const* d_in, const int* in_sizes, int n_in,
                              void* d_out, int out_size, void* d_ws, size_t ws_size,
                              hipStream_t stream) {
  const float* x    = (const float*)d_in[0];
  const float* xnrm = (const float*)d_in[1];
  const float* refv = (const float*)d_in[2];
  float* out = (float*)d_out;
  const int B = in_sizes[0] / NN;  // 2048
  sinkhorn_wave<<<dim3(B), dim3(64), 0, stream>>>(x, xnrm, refv, out);
}

// Round 5
// 20.555 us; speedup vs baseline: 6.8788x; 1.0285x over previous
//
#include <hip/hip_runtime.h>

#define NN 256
#define NITER 20
static constexpr float KK = 14.426950408889634f; // (1/tau)*log2(e), tau=0.1

template<int CTRL, int RM>
__device__ __forceinline__ float dppadd(float x) {
  int v = __builtin_amdgcn_update_dpp(0, __float_as_int(x), CTRL, RM, 0xF, true);
  return x + __int_as_float(v);
}
template<int CTRL, int RM>
__device__ __forceinline__ int dppaddi(int x) {
  int v = __builtin_amdgcn_update_dpp(0, x, CTRL, RM, 0xF, true);
  return x + v;
}
__device__ __forceinline__ float rlane(float v, int l) {
  return __int_as_float(__builtin_amdgcn_readlane(__float_as_int(v), l));
}
__device__ __forceinline__ float rcpf(float x) {
  float r; asm("v_rcp_f32 %0, %1" : "=v"(r) : "v"(x)); return r;
}
// Bank-conflict-killing bijective swizzle for the float2 W array.
// slot s -> index s + (s>>4). For diagonal queries s≈4L+t this spreads the
// 16 previously-colliding lanes across 16 distinct bank-pairs.
__device__ __forceinline__ int swz(int s) { return s + (s >> 4); }

__global__ __launch_bounds__(64)
void sinkhorn_wave(const float* __restrict__ x,
                   const float* __restrict__ xn,
                   const float* __restrict__ refv,
                   float* __restrict__ out)
{
  // Single-wave workgroup: no __syncthreads. Per-wave in-order DS processing
  // guarantees LDS RAW ordering.
  __shared__ __align__(16) float2   W[274];     // swizzled; slot s at W[swz(s)], s in [0,256]
  __shared__ __align__(16) unsigned hist[NN];   // bucket counts
  __shared__ __align__(16) int      exclArr[NN];// exclusive bucket prefix
  __shared__ __align__(16) float    xsArr[NN];  // bucket-grouped clamped xn
  __shared__ __align__(16) int      origArr[NN];// original row index per slot

  const int lane = threadIdx.x;   // 0..63
  const int b = blockIdx.x;
  const int j4 = lane * 4;
  const size_t base = (size_t)b * NN;

  float xnv[4], xv[4], rv[4];
  { float4 t = *(const float4*)(xn + base + j4); xnv[0]=t.x; xnv[1]=t.y; xnv[2]=t.z; xnv[3]=t.w; }
  { float4 t = *(const float4*)(x  + base + j4); xv[0]=t.x;  xv[1]=t.y;  xv[2]=t.z;  xv[3]=t.w; }
  { float4 t = *(const float4*)(refv + j4);      rv[0]=t.x;  rv[1]=t.y;  rv[2]=t.z;  rv[3]=t.w; }

  // ---- bucket-group rows by grid cell (intra-bucket order is free) ----
  *(uint4*)&hist[j4] = make_uint4(0u, 0u, 0u, 0u);
  float vc[4]; int cb[4]; unsigned rtn[4];
  #pragma unroll
  for (int t = 0; t < 4; ++t) {
    vc[t] = fminf(fmaxf(xnv[t], -1.0f), 1.0f);     // clamp = exact row-shift invariance
    cb[t] = (int)fmaf(vc[t], 127.5f, 127.5f);      // bucket in [0,255]
    rtn[t] = atomicAdd(&hist[cb[t]], 1u);          // intra-bucket position
  }
  uint4 hv = *(uint4*)&hist[j4];
  int ih0 = (int)hv.x, ih1 = ih0 + (int)hv.y, ih2 = ih1 + (int)hv.z, ih3 = ih2 + (int)hv.w;
  int sH = ih3;
  sH = dppaddi<0x111, 0xF>(sH);
  sH = dppaddi<0x112, 0xF>(sH);
  sH = dppaddi<0x114, 0xF>(sH);
  sH = dppaddi<0x118, 0xF>(sH);
  sH = dppaddi<0x142, 0xA>(sH);   // ROW_BCAST15 -> rows 1,3
  sH = dppaddi<0x143, 0xC>(sH);   // ROW_BCAST31 -> rows 2,3
  const int offH = sH - ih3;
  int slotM[4] = { offH, offH + ih0, offH + ih1, offH + ih2 };  // col-pass raw slots (lane-own)
  *(int4*)&exclArr[j4] = make_int4(slotM[0], slotM[1], slotM[2], slotM[3]);
  #pragma unroll
  for (int t = 0; t < 4; ++t) {
    int slot = exclArr[cb[t]] + (int)rtn[t];
    xsArr[slot]   = vc[t];
    origArr[slot] = j4 + t;
  }
  float xs[4]; int orig[4];
  { float4 t = *(float4*)&xsArr[j4]; xs[0]=t.x; xs[1]=t.y; xs[2]=t.z; xs[3]=t.w; }
  { int4  t = *(int4*)&origArr[j4]; orig[0]=t.x; orig[1]=t.y; orig[2]=t.z; orig[3]=t.w; }

  // precompute SWIZZLED iteration-invariant gather slots
  int slotJ[4];
  #pragma unroll
  for (int t = 0; t < 4; ++t) {
    slotJ[t] = swz((int)fmaf(xs[t], 127.5f, 127.5f) + 1);  // row-pass: bucket(xs)+1
    slotM[t] = swz(slotM[t]);                              // col-pass
  }

  // precomputed exponential factors (setup-only transcendentals)
  float Ep[4], Em[4], Epx[4], Emx[4];
  #pragma unroll
  for (int t = 0; t < 4; ++t) {
    Ep[t]  = exp2f( KK * rv[t]);  Em[t]  = exp2f(-KK * rv[t]);
    Epx[t] = exp2f( KK * xs[t]);  Emx[t] = exp2f(-KK * xs[t]);
  }

  const int wbase = swz(j4);      // 4L..4L+3 never cross a 16-slot boundary
  // scan + store: W[swz(s)] = (P_excl[s], Q_incl[s]) for s in [0,256]
  auto scan_store = [&](float pa0, float pa1, float pa2, float pa3,
                        float qb0, float qb1, float qb2, float qb3) {
    float ip0 = pa0, ip1 = ip0 + pa1, ip2 = ip1 + pa2, ip3 = ip2 + pa3;
    float sq3 = qb3, sq2 = sq3 + qb2, sq1 = sq2 + qb1, sq0 = sq1 + qb0;
    float sP = ip3;                     // inclusive prefix over lane totals
    sP = dppadd<0x111, 0xF>(sP);
    sP = dppadd<0x112, 0xF>(sP);
    sP = dppadd<0x114, 0xF>(sP);
    sP = dppadd<0x118, 0xF>(sP);
    sP = dppadd<0x142, 0xA>(sP);
    sP = dppadd<0x143, 0xC>(sP);
    float offP = sP - ip3;
    float sQ = sq0;                     // inclusive suffix within rows
    sQ = dppadd<0x101, 0xF>(sQ);
    sQ = dppadd<0x102, 0xF>(sQ);
    sQ = dppadd<0x104, 0xF>(sQ);
    sQ = dppadd<0x108, 0xF>(sQ);
    float q1 = rlane(sQ, 16), q2 = rlane(sQ, 32), q3 = rlane(sQ, 48);
    int row = lane >> 4;
    float offQ = sQ - sq0;
    offQ += (row < 1) ? q1 : 0.f;
    offQ += (row < 2) ? q2 : 0.f;
    offQ += (row < 3) ? q3 : 0.f;
    float4 w0 = make_float4(offP,       offQ + sq0, offP + ip0, offQ + sq1);
    float4 w1 = make_float4(offP + ip1, offQ + sq2, offP + ip2, offQ + sq3);
    *(float4*)&W[wbase]     = w0;
    *(float4*)&W[wbase + 2] = w1;
    if (lane == 63) W[272] = make_float2(sP, 0.f);   // swz(256) = 272
  };

  float vC[4] = {1.f, 1.f, 1.f, 1.f}, vR[4];
  #pragma unroll 1
  for (int it = 0; it < NITER; ++it) {
    // row pass: vR[m] = 1 / (Emx*P_excl[slotJ] + Epx*Q_incl[slotJ])
    scan_store(Ep[0]*vC[0], Ep[1]*vC[1], Ep[2]*vC[2], Ep[3]*vC[3],
               Em[0]*vC[0], Em[1]*vC[1], Em[2]*vC[2], Em[3]*vC[3]);
    #pragma unroll
    for (int t = 0; t < 4; ++t) {
      float2 w = W[slotJ[t]];
      vR[t] = rcpf(fmaf(Emx[t], w.x, Epx[t] * w.y));
    }
    // col pass: vC[j] = 1 / (Em*P_excl[slotM] + Ep*Q_incl[slotM])
    scan_store(Epx[0]*vR[0], Epx[1]*vR[1], Epx[2]*vR[2], Epx[3]*vR[3],
               Emx[0]*vR[0], Emx[1]*vR[1], Emx[2]*vR[2], Emx[3]*vR[3]);
    #pragma unroll
    for (int t = 0; t < 4; ++t) {
      float2 w = W[slotM[t]];
      vC[t] = rcpf(fmaf(Em[t], w.x, Ep[t] * w.y));
    }
  }
  // final weighted row pass: out[orig_m] = vR_m * sum_j 2^{-k|xs_m-ref_j|} vC_j x_j
  {
    float g0 = vC[0]*xv[0], g1 = vC[1]*xv[1], g2 = vC[2]*xv[2], g3 = vC[3]*xv[3];
    scan_store(Ep[0]*g0, Ep[1]*g1, Ep[2]*g2, Ep[3]*g3,
               Em[0]*g0, Em[1]*g1, Em[2]*g2, Em[3]*g3);
    #pragma unroll
    for (int t = 0; t < 4; ++t) {
      float2 w = W[slotJ[t]];
      float S = fmaf(Emx[t], w.x, Epx[t] * w.y);
      out[base + orig[t]] = vR[t] * S;
    }
  }
}

extern "C" void kernel_launch(void* const* d_in, const int* in_sizes, int n_in,
                              void* d_out, int out_size, void* d_ws, size_t ws_size,
                              hipStream_t stream) {
  const float* x    = (const float*)d_in[0];
  const float* xnrm = (const float*)d_in[1];
  const float* refv = (const float*)d_in[2];
  float* out = (float*)d_out;
  const int B = in_sizes[0] / NN;  // 2048
  sinkhorn_wave<<<dim3(B), dim3(64), 0, stream>>>(x, xnrm, refv, out);
}